// Round 2
// baseline (35909.360 us; speedup 1.0000x reference)
//
#include <hip/hip_runtime.h>

// 2-layer GRU, I=8, H=128, T=32768 sequential steps, out = final h1 (128 f32).
// Pipeline over CUs (layer1 never feeds layer0):
//   block 0     W0  : layer-0 recurrence (w_hh0 in regs), consumes gi0 stream,
//                     publishes h0 stream
//   blocks 2..5 army: gi0[t] = w_ih0@x[t]+b_ih0 (x-only) and
//                     gi1[t] = w_ih1@h0[t]+b_ih1 (parallel over groups, mod-4)
//   block 1     W1  : layer-1 recurrence (w_hh1 in regs), consumes gi1 stream
// Streams in LLC rings (d_ws) guarded by per-group (8-step) agent-scope flags.

#define T_STEPS 32768
#define GS 8
#define NG (T_STEPS / GS)
#define NARMY 4
#define HDIM 128
#define SCOPE_AGENT __HIP_MEMORY_SCOPE_AGENT

typedef __attribute__((ext_vector_type(2))) float f32x2;
typedef __attribute__((ext_vector_type(4))) float f32x4;

__device__ __forceinline__ f32x2 lo2(f32x4 v) { return __builtin_shufflevector(v, v, 0, 1); }
__device__ __forceinline__ f32x2 hi2(f32x4 v) { return __builtin_shufflevector(v, v, 2, 3); }
__device__ __forceinline__ f32x4 mk4(float a, float b, float c) {
  f32x4 v = {a, b, c, 0.f};
  return v;
}
__device__ __forceinline__ void pkfma(f32x2& acc, f32x2 a, f32x2 b) {
  asm("v_pk_fma_f32 %0, %1, %2, %0" : "+v"(acc) : "v"(a), "v"(b));
}
__device__ __forceinline__ float sigm(float x) {
  return __fdividef(1.f, 1.f + __expf(-x));
}
__device__ __forceinline__ float tanh_fast(float x) {
  x = fminf(15.f, fmaxf(-15.f, x));
  float e = __expf(2.f * x);
  return (e - 1.f) * __fdividef(1.f, e + 1.f);
}
__device__ __forceinline__ float red4(float v) {
  v += __shfl_xor(v, 1);
  v += __shfl_xor(v, 2);
  return v;
}

// Thread t: q=t&3 (32-float h chunk), u=t>>2 (hidden unit; rows u,u+128,u+256).
// Weights stored PRE-ROTATED: slot r holds source vector k = r ^ 2q, so the
// inner loop pairs w[r] (static index) with an h read at k (address math only)
// -> bank-conflict-free across q AND no runtime-indexed register arrays.
__device__ __forceinline__ void load_w3(const float* __restrict__ W, int u, int q,
                                        f32x4 (&w0)[8], f32x4 (&w1)[8], f32x4 (&w2)[8]) {
  #pragma unroll
  for (int r = 0; r < 8; ++r) {
    const int k = r ^ (q << 1);
    const int col = 32 * q + 4 * k;
    w0[r] = *(const f32x4*)(W + (size_t)u * 128 + col);
    w1[r] = *(const f32x4*)(W + (size_t)(u + 128) * 128 + col);
    w2[r] = *(const f32x4*)(W + (size_t)(u + 256) * 128 + col);
  }
}

__device__ __forceinline__ void dot3_pk(const f32x4 (&w0)[8], const f32x4 (&w1)[8],
                                        const f32x4 (&w2)[8], const float* hb, int q,
                                        float& a0, float& a1, float& a2) {
  f32x2 c0 = {0.f, 0.f}, c1 = {0.f, 0.f}, c2 = {0.f, 0.f};
  const int base = 32 * q;
  #pragma unroll
  for (int r = 0; r < 8; ++r) {
    const int k = r ^ (q << 1);
    f32x4 h4 = *(const f32x4*)(hb + base + 4 * k);
    f32x2 hl = lo2(h4), hh = hi2(h4);
    pkfma(c0, lo2(w0[r]), hl); pkfma(c0, hi2(w0[r]), hh);
    pkfma(c1, lo2(w1[r]), hl); pkfma(c1, hi2(w1[r]), hh);
    pkfma(c2, lo2(w2[r]), hl); pkfma(c2, hi2(w2[r]), hh);
  }
  a0 = red4(c0.x + c0.y);
  a1 = red4(c1.x + c1.y);
  a2 = red4(c2.x + c2.y);
}

// ======================= W0: layer-0 recurrence =======================
__device__ __noinline__ void role_w0(const float* __restrict__ w_hh0,
                                     const float* __restrict__ b_hh0,
                                     const unsigned* flags_gi0, const unsigned* w1_prog,
                                     unsigned* flags_h0, const f32x4* __restrict__ gi0_ring,
                                     float* __restrict__ h0_ring, int ring_steps) {
  __shared__ __align__(16) float hbuf[2 * HDIM];
  const int tid = threadIdx.x, q = tid & 3, u = tid >> 2;
  if (tid < HDIM) { hbuf[tid] = 0.f; hbuf[HDIM + tid] = 0.f; }
  __syncthreads();
  f32x4 w0[8], w1[8], w2[8];
  load_w3(w_hh0, u, q, w0, w1, w2);
  const float bhr = b_hh0[u], bhz = b_hh0[u + 128], bhn = b_hh0[u + 256];
  const int rmask = ring_steps - 1, ring_groups = ring_steps / GS;

  f32x4 gv[GS], gvn[GS];
  bool have = false;
  int w1_seen = 0;
  for (int g = 0; g < NG; ++g) {
    while (g - w1_seen >= ring_groups) {  // ring back-pressure via W1 progress
      w1_seen = (int)__hip_atomic_load(w1_prog, __ATOMIC_RELAXED, SCOPE_AGENT);
      __builtin_amdgcn_s_sleep(2);
    }
    if (have) {
      #pragma unroll
      for (int s = 0; s < GS; ++s) gv[s] = gvn[s];
    } else {
      while (__hip_atomic_load(&flags_gi0[g], __ATOMIC_ACQUIRE, SCOPE_AGENT) == 0u)
        __builtin_amdgcn_s_sleep(2);
      if (q == 0) {
        #pragma unroll
        for (int s = 0; s < GS; ++s)
          gv[s] = gi0_ring[(size_t)((g * GS + s) & rmask) * HDIM + u];
      }
    }
    have = false;
    if (g + 1 < NG &&
        __hip_atomic_load(&flags_gi0[g + 1], __ATOMIC_ACQUIRE, SCOPE_AGENT) != 0u) {
      if (q == 0) {
        #pragma unroll
        for (int s = 0; s < GS; ++s)
          gvn[s] = gi0_ring[(size_t)(((g + 1) * GS + s) & rmask) * HDIM + u];
      }
      have = true;
    }
    #pragma unroll
    for (int s = 0; s < GS; ++s) {
      const int pr = s & 1;
      float a0, a1, a2;
      dot3_pk(w0, w1, w2, hbuf + pr * HDIM, q, a0, a1, a2);
      if (q == 0) {
        const float r = sigm(gv[s].x + a0 + bhr);
        const float z = sigm(gv[s].y + a1 + bhz);
        const float n = tanh_fast(gv[s].z + r * (a2 + bhn));
        const float hp = hbuf[pr * HDIM + u];
        const float hn_ = (1.f - z) * n + z * hp;
        hbuf[(pr ^ 1) * HDIM + u] = hn_;
        h0_ring[(size_t)((g * GS + s) & rmask) * HDIM + u] = hn_;
      }
      __syncthreads();
    }
    __threadfence();
    __syncthreads();
    if (tid == 0)
      __hip_atomic_store(&flags_h0[g], 1u, __ATOMIC_RELEASE, SCOPE_AGENT);
  }
}

// ======================= W1: layer-1 recurrence =======================
__device__ __noinline__ void role_w1(const float* __restrict__ w_hh1,
                                     const float* __restrict__ b_hh1,
                                     const unsigned* flags_gi1, unsigned* w1_prog,
                                     const f32x4* __restrict__ gi1_ring,
                                     float* __restrict__ out, int ring_steps) {
  __shared__ __align__(16) float hbuf[2 * HDIM];
  const int tid = threadIdx.x, q = tid & 3, u = tid >> 2;
  if (tid < HDIM) { hbuf[tid] = 0.f; hbuf[HDIM + tid] = 0.f; }
  __syncthreads();
  f32x4 w0[8], w1[8], w2[8];
  load_w3(w_hh1, u, q, w0, w1, w2);
  const float bhr = b_hh1[u], bhz = b_hh1[u + 128], bhn = b_hh1[u + 256];
  const int rmask = ring_steps - 1;

  f32x4 gv[GS], gvn[GS];
  bool have = false;
  for (int g = 0; g < NG; ++g) {
    if (have) {
      #pragma unroll
      for (int s = 0; s < GS; ++s) gv[s] = gvn[s];
    } else {
      while (__hip_atomic_load(&flags_gi1[g], __ATOMIC_ACQUIRE, SCOPE_AGENT) == 0u)
        __builtin_amdgcn_s_sleep(2);
      if (q == 0) {
        #pragma unroll
        for (int s = 0; s < GS; ++s)
          gv[s] = gi1_ring[(size_t)((g * GS + s) & rmask) * HDIM + u];
      }
    }
    have = false;
    if (g + 1 < NG &&
        __hip_atomic_load(&flags_gi1[g + 1], __ATOMIC_ACQUIRE, SCOPE_AGENT) != 0u) {
      if (q == 0) {
        #pragma unroll
        for (int s = 0; s < GS; ++s)
          gvn[s] = gi1_ring[(size_t)(((g + 1) * GS + s) & rmask) * HDIM + u];
      }
      have = true;
    }
    #pragma unroll
    for (int s = 0; s < GS; ++s) {
      const int pr = s & 1;
      float a0, a1, a2;
      dot3_pk(w0, w1, w2, hbuf + pr * HDIM, q, a0, a1, a2);
      if (q == 0) {
        const float r = sigm(gv[s].x + a0 + bhr);
        const float z = sigm(gv[s].y + a1 + bhz);
        const float n = tanh_fast(gv[s].z + r * (a2 + bhn));
        const float hp = hbuf[pr * HDIM + u];
        const float hn_ = (1.f - z) * n + z * hp;
        hbuf[(pr ^ 1) * HDIM + u] = hn_;
        if (g == NG - 1 && s == GS - 1) out[u] = hn_;
      }
      __syncthreads();
    }
    if ((g & 7) == 7 && tid == 0)
      __hip_atomic_store(w1_prog, (unsigned)(g + 1), __ATOMIC_RELAXED, SCOPE_AGENT);
  }
}

// ============== army: gi0 (x-only) and gi1 (needs h0 stream) ==============
__device__ __noinline__ void role_army(int a, const float* __restrict__ x,
                                       const float* __restrict__ w_ih0,
                                       const float* __restrict__ b_ih0,
                                       const float* __restrict__ w_ih1,
                                       const float* __restrict__ b_ih1,
                                       const unsigned* flags_h0, unsigned* flags_gi0,
                                       unsigned* flags_gi1,
                                       const float* __restrict__ h0_ring,
                                       f32x4* __restrict__ gi0_ring,
                                       f32x4* __restrict__ gi1_ring, int ring_steps) {
  const int tid = threadIdx.x, q = tid & 3, u = tid >> 2;
  const int rmask = ring_steps - 1;
  f32x4 w0[8], w1[8], w2[8];
  load_w3(w_ih1, u, q, w0, w1, w2);
  const float bir = b_ih1[u], biz = b_ih1[u + 128], bin1 = b_ih1[u + 256];
  float wi0[8], wi1[8], wi2[8];
  float bi0 = 0.f, bi1 = 0.f, bi2 = 0.f;
  if (tid < HDIM) {
    #pragma unroll
    for (int i = 0; i < 8; ++i) {
      wi0[i] = w_ih0[tid * 8 + i];
      wi1[i] = w_ih0[(tid + 128) * 8 + i];
      wi2[i] = w_ih0[(tid + 256) * 8 + i];
    }
    bi0 = b_ih0[tid]; bi1 = b_ih0[tid + 128]; bi2 = b_ih0[tid + 256];
  }

  for (int g = a; g < NG; g += NARMY) {
    // gi0 for group g (depends only on x)
    if (tid < HDIM) {
      #pragma unroll
      for (int s = 0; s < GS; ++s) {
        const float* xp = x + (size_t)(g * GS + s) * 8;
        float r = bi0, z = bi1, n = bi2;
        #pragma unroll
        for (int i = 0; i < 8; ++i) {
          const float xv = xp[i];
          r = fmaf(wi0[i], xv, r);
          z = fmaf(wi1[i], xv, z);
          n = fmaf(wi2[i], xv, n);
        }
        gi0_ring[(size_t)((g * GS + s) & rmask) * HDIM + tid] = mk4(r, z, n);
      }
    }
    __threadfence();
    __syncthreads();
    if (tid == 0)
      __hip_atomic_store(&flags_gi0[g], 1u, __ATOMIC_RELEASE, SCOPE_AGENT);

    // gi1 for group g (needs h0)
    while (__hip_atomic_load(&flags_h0[g], __ATOMIC_ACQUIRE, SCOPE_AGENT) == 0u)
      __builtin_amdgcn_s_sleep(2);
    #pragma unroll
    for (int s = 0; s < GS; ++s) {
      const int t = g * GS + s;
      const float* hb = h0_ring + (size_t)(t & rmask) * HDIM;
      float a0, a1, a2;
      dot3_pk(w0, w1, w2, hb, q, a0, a1, a2);
      if (q == 0)
        gi1_ring[(size_t)(t & rmask) * HDIM + u] = mk4(a0 + bir, a1 + biz, a2 + bin1);
    }
    __threadfence();
    __syncthreads();
    if (tid == 0)
      __hip_atomic_store(&flags_gi1[g], 1u, __ATOMIC_RELEASE, SCOPE_AGENT);
  }
}

__global__ __launch_bounds__(512, 2)
void unitrnn_pipe(const float* __restrict__ x,
                  const float* __restrict__ w_ih0, const float* __restrict__ w_hh0,
                  const float* __restrict__ b_ih0, const float* __restrict__ b_hh0,
                  const float* __restrict__ w_ih1, const float* __restrict__ w_hh1,
                  const float* __restrict__ b_ih1, const float* __restrict__ b_hh1,
                  float* __restrict__ out,
                  unsigned* flags_h0, unsigned* flags_gi1, unsigned* flags_gi0,
                  unsigned* w1_prog, float* h0_ring, f32x4* gi0_ring,
                  f32x4* gi1_ring, int ring_steps) {
  const int bid = blockIdx.x;
  if (bid == 0)
    role_w0(w_hh0, b_hh0, flags_gi0, w1_prog, flags_h0, gi0_ring, h0_ring, ring_steps);
  else if (bid == 1)
    role_w1(w_hh1, b_hh1, flags_gi1, w1_prog, gi1_ring, out, ring_steps);
  else
    role_army(bid - 2, x, w_ih0, b_ih0, w_ih1, b_ih1, flags_h0, flags_gi0,
              flags_gi1, h0_ring, gi0_ring, gi1_ring, ring_steps);
}

extern "C" void kernel_launch(void* const* d_in, const int* in_sizes, int n_in,
                              void* d_out, int out_size, void* d_ws, size_t ws_size,
                              hipStream_t stream) {
  (void)in_sizes; (void)n_in; (void)out_size;
  const float* x     = (const float*)d_in[0];
  const float* w_ih0 = (const float*)d_in[1];
  const float* w_hh0 = (const float*)d_in[2];
  const float* b_ih0 = (const float*)d_in[3];
  const float* b_hh0 = (const float*)d_in[4];
  const float* w_ih1 = (const float*)d_in[5];
  const float* w_hh1 = (const float*)d_in[6];
  const float* b_ih1 = (const float*)d_in[7];
  const float* b_hh1 = (const float*)d_in[8];
  float* out = (float*)d_out;

  // flags: h0[NG], gi1[NG], gi0[NG], w1_prog — all zeroed each launch
  const size_t flags_bytes = (((size_t)3 * NG + 1) * sizeof(unsigned) + 255) & ~(size_t)255;
  // per ring step: h0 128 f32 (512B) + gi0 128 f32x4 (2KB) + gi1 128 f32x4 (2KB)
  int ring_steps = 1024;
  while (ring_steps > 16 &&
         flags_bytes + (size_t)ring_steps * 4608 > ws_size)
    ring_steps >>= 1;

  unsigned* flags_h0  = (unsigned*)d_ws;
  unsigned* flags_gi1 = flags_h0 + NG;
  unsigned* flags_gi0 = flags_gi1 + NG;
  unsigned* w1_prog   = flags_gi0 + NG;
  float* h0_ring  = (float*)((char*)d_ws + flags_bytes);
  f32x4* gi0_ring = (f32x4*)(h0_ring + (size_t)ring_steps * HDIM);
  f32x4* gi1_ring = gi0_ring + (size_t)ring_steps * HDIM;

  hipMemsetAsync(d_ws, 0, flags_bytes, stream);
  hipLaunchKernelGGL(unitrnn_pipe, dim3(2 + NARMY), dim3(512), 0, stream,
                     x, w_ih0, w_hh0, b_ih0, b_hh0,
                     w_ih1, w_hh1, b_ih1, b_hh1, out,
                     flags_h0, flags_gi1, flags_gi0, w1_prog,
                     h0_ring, gi0_ring, gi1_ring, ring_steps);
}